// Round 1
// baseline (1908.165 us; speedup 1.0000x reference)
//
#include <hip/hip_runtime.h>

// DiscreteContinuousConvS2: out[bc, k, t, p] = sum_{j in seg(k,t)} v_j * x[bc, lat_j, (lon_j - 1 - p) mod 720]
// B*C = 128, K = 3, nlat = 361, nlon = 720.

#define NLAT 361
#define NLON 720
#define KK 3
#define NSEG (KK * NLAT) // 1083
#define BCDIM 128
#define NBC 8
#define CHUNK 512

__global__ void zero_counts_kernel(int* counts) {
    int i = blockIdx.x * 256 + threadIdx.x;
    if (i < NSEG) counts[i] = 0;
}

__global__ void hist_kernel(const int* __restrict__ pk, const int* __restrict__ pt,
                            int nnz, int* __restrict__ counts) {
    int i = blockIdx.x * 256 + threadIdx.x;
    if (i < nnz) atomicAdd(&counts[pk[i] * NLAT + pt[i]], 1);
}

// Single-block exclusive scan over 1083 counts -> offs[0..1083], cursor copy.
__global__ void scan_kernel(const int* __restrict__ counts, int* __restrict__ offs,
                            int* __restrict__ cursor) {
    __shared__ int part[256];
    int tid = threadIdx.x;
    int c[5];
    int s = 0;
    int i0 = tid * 5;
#pragma unroll
    for (int u = 0; u < 5; ++u) {
        int idx = i0 + u;
        int v = (idx < NSEG) ? counts[idx] : 0;
        c[u] = v;
        s += v;
    }
    part[tid] = s;
    __syncthreads();
    // Hillis-Steele inclusive scan over 256 partials
    for (int d = 1; d < 256; d <<= 1) {
        int v = part[tid];
        int w = (tid >= d) ? part[tid - d] : 0;
        __syncthreads();
        part[tid] = v + w;
        __syncthreads();
    }
    int excl = part[tid] - s;
#pragma unroll
    for (int u = 0; u < 5; ++u) {
        int idx = i0 + u;
        if (idx < NSEG) {
            offs[idx] = excl;
            cursor[idx] = excl;
        }
        excl += c[u];
    }
    if (tid == 255) offs[NSEG] = excl;
}

// Scatter taps into CSR order. Pack: ((la*720 + lon) << 10) | lon  (fits: 18+10 bits)
__global__ void scatter_kernel(const int* __restrict__ pk, const int* __restrict__ pt,
                               const int* __restrict__ pla, const int* __restrict__ plo,
                               const float* __restrict__ pv, int nnz,
                               int* __restrict__ cursor, int* __restrict__ tapPack,
                               float* __restrict__ tapVal) {
    int i = blockIdx.x * 256 + threadIdx.x;
    if (i < nnz) {
        int s = pk[i] * NLAT + pt[i];
        int pos = atomicAdd(&cursor[s], 1);
        int la = pla[i];
        int lo = plo[i];
        tapPack[pos] = ((la * NLON + lo) << 10) | lo;
        tapVal[pos] = pv[i];
    }
}

// Main gather kernel.
// grid: (48, 1083) ; blockIdx.x -> {p-tile (3), bc-chunk (16)} ; blockIdx.y -> segment s
// block: 256 threads, thread = p within p-tile; NBC=8 bc accumulators per thread.
__global__ __launch_bounds__(256) void dconv_main_kernel(
    const float* __restrict__ x, const int* __restrict__ offs,
    const int* __restrict__ tapPack, const float* __restrict__ tapVal,
    float* __restrict__ out) {
    __shared__ int sPack[CHUNK];
    __shared__ float sVal[CHUNK];

    int s = blockIdx.y;
    int pt = blockIdx.x % 3;
    int bcc = blockIdx.x / 3;
    int p = pt * 256 + threadIdx.x;
    int bc0 = bcc * NBC;

    int j0 = offs[s];
    int j1 = offs[s + 1];

    float acc[NBC];
#pragma unroll
    for (int b = 0; b < NBC; ++b) acc[b] = 0.f;

    int pp1 = p + 1;

    for (int base = j0; base < j1; base += CHUNK) {
        int cnt = min(CHUNK, j1 - base);
        for (int u = threadIdx.x; u < cnt; u += 256) {
            sPack[u] = tapPack[base + u];
            sVal[u] = tapVal[base + u];
        }
        __syncthreads();
        if (p < NLON) {
            for (int u = 0; u < cnt; ++u) {
                int pk = sPack[u];
                float v = sVal[u];
                int lo = pk & 1023;
                int A = pk >> 10;
                int c = lo - pp1;
                int idx = A - pp1 + ((c < 0) ? NLON : 0); // la*720 + ((lon-1-p) mod 720)
#pragma unroll
                for (int b = 0; b < NBC; ++b) {
                    acc[b] = fmaf(v, x[(bc0 + b) * (NLAT * NLON) + idx], acc[b]);
                }
            }
        }
        __syncthreads();
    }

    if (p < NLON) {
#pragma unroll
        for (int b = 0; b < NBC; ++b) {
            out[((bc0 + b) * NSEG + s) * NLON + p] = acc[b];
        }
    }
}

extern "C" void kernel_launch(void* const* d_in, const int* in_sizes, int n_in,
                              void* d_out, int out_size, void* d_ws, size_t ws_size,
                              hipStream_t stream) {
    const float* x = (const float*)d_in[0];
    const float* pv = (const float*)d_in[1];
    const int* pk = (const int*)d_in[2];
    const int* pt = (const int*)d_in[3];
    const int* pla = (const int*)d_in[4];
    const int* plo = (const int*)d_in[5];
    float* out = (float*)d_out;

    int nnz = in_sizes[1];
    int nnz_pad = (nnz + 255) & ~255;

    int* wsI = (int*)d_ws;
    int* counts = wsI;          // [1083]
    int* offs = wsI + 1088;     // [1084]
    int* cursor = wsI + 2176;   // [1083]
    int* tapPack = wsI + 4096;  // [nnz]
    float* tapVal = (float*)(wsI + 4096 + nnz_pad); // [nnz]

    zero_counts_kernel<<<(NSEG + 255) / 256, 256, 0, stream>>>(counts);
    hist_kernel<<<(nnz + 255) / 256, 256, 0, stream>>>(pk, pt, nnz, counts);
    scan_kernel<<<1, 256, 0, stream>>>(counts, offs, cursor);
    scatter_kernel<<<(nnz + 255) / 256, 256, 0, stream>>>(pk, pt, pla, plo, pv, nnz,
                                                          cursor, tapPack, tapVal);

    dim3 grid(48, NSEG, 1);
    dconv_main_kernel<<<grid, 256, 0, stream>>>(x, offs, tapPack, tapVal, out);
}

// Round 2
// 1215.283 us; speedup vs baseline: 1.5701x; 1.5701x over previous
//
#include <hip/hip_runtime.h>

// DiscreteContinuousConvS2:
// out[bc, k, t, p] = sum_{taps (k,t,la,lo)} v * x[bc, la, (lo - 1 - p) mod 720]
// B*C = 128, K = 3, nlat_in = nlat_out = 361, nlon = 720.
//
// Restructured: for each (t, la) the tap set over lo is a contiguous interval
// (theta(lo) unimodal). Build a dense float4 weight stream (w_k0,w_k1,w_k2,0)
// per (t,la) window, then run a sliding-window FIR along lon with all 3 k's
// fused and 4-wide lon vectorization (dwordx4 x loads, 4B-aligned).

#define NLAT 361
#define NLON 720
#define KK 3
#define LASPAN 9                  // la - t in [-4, 4] (math says [-3,3]; margin)
#define NROWS (NLAT * LASPAN)     // 3249
#define CAP 524288                // max total window slots (actual ~0.1-0.2M)
#define NBC 8

typedef float f4u __attribute__((ext_vector_type(4), aligned(4)));

// ---------------- build kernels ----------------

__global__ void init_rows_kernel(int* __restrict__ rmin, int* __restrict__ rmax) {
    int i = blockIdx.x * 256 + threadIdx.x;
    if (i < NROWS) { rmin[i] = NLON; rmax[i] = -1; }
}

__global__ void minmax_kernel(const int* __restrict__ pt, const int* __restrict__ pla,
                              const int* __restrict__ plo, int nnz,
                              int* __restrict__ rmin, int* __restrict__ rmax) {
    int i = blockIdx.x * 256 + threadIdx.x;
    if (i >= nnz) return;
    int t = pt[i], la = pla[i], lo = plo[i];
    int d = la - t + 4;
    if (d < 0 || d >= LASPAN) return;  // impossible by geometry; safety
    int row = t * LASPAN + d;
    atomicMin(&rmin[row], lo);
    atomicMax(&rmax[row], lo);
}

// Single-block exclusive scan of row widths -> offs[0..NROWS]
__global__ void scan_rows_kernel(const int* __restrict__ rmin, const int* __restrict__ rmax,
                                 int* __restrict__ offs) {
    __shared__ int part[256];
    int tid = threadIdx.x;
    int c[13];
    int s = 0;
    int i0 = tid * 13;
#pragma unroll
    for (int u = 0; u < 13; ++u) {
        int idx = i0 + u;
        int w = 0;
        if (idx < NROWS) {
            w = rmax[idx] - rmin[idx] + 1;
            if (w < 0) w = 0;
        }
        c[u] = w;
        s += w;
    }
    part[tid] = s;
    __syncthreads();
    for (int d = 1; d < 256; d <<= 1) {
        int v = part[tid];
        int w = (tid >= d) ? part[tid - d] : 0;
        __syncthreads();
        part[tid] = v + w;
        __syncthreads();
    }
    int excl = part[tid] - s;
#pragma unroll
    for (int u = 0; u < 13; ++u) {
        int idx = i0 + u;
        if (idx < NROWS) offs[idx] = excl;
        excl += c[u];
    }
    if (tid == 255) offs[NROWS] = excl;
}

__global__ void zero_stream_kernel(const int* __restrict__ offs, float4* __restrict__ stream4) {
    int total = offs[NROWS];
    if (total > CAP) total = CAP;
    for (int i = blockIdx.x * 256 + threadIdx.x; i < total; i += gridDim.x * 256)
        stream4[i] = make_float4(0.f, 0.f, 0.f, 0.f);
}

__global__ void scatter_w_kernel(const int* __restrict__ pk, const int* __restrict__ pt,
                                 const int* __restrict__ pla, const int* __restrict__ plo,
                                 const float* __restrict__ pv, int nnz,
                                 const int* __restrict__ rmin, const int* __restrict__ offs,
                                 float* __restrict__ stream) {
    int i = blockIdx.x * 256 + threadIdx.x;
    if (i >= nnz) return;
    int t = pt[i], la = pla[i], lo = plo[i], k = pk[i];
    int d = la - t + 4;
    if (d < 0 || d >= LASPAN) return;
    int row = t * LASPAN + d;
    int slot = offs[row] + (lo - rmin[row]);
    if (slot >= 0 && slot < CAP && k >= 0 && k < 4)
        stream[(size_t)slot * 4 + k] = pv[i];
}

// ---------------- main FIR kernel ----------------
// grid: (48, 361); blockIdx.x = ptile(3) x bcc(16); blockIdx.y = t
// 256 threads; thread -> one p; NBC=8 bc-planes in registers; k fused (3 acc).

__global__ __launch_bounds__(256) void dconv_fir_kernel(
    const float* __restrict__ x, const int* __restrict__ rmin_a,
    const int* __restrict__ rmax_a, const int* __restrict__ offs,
    const float* __restrict__ stream, float* __restrict__ out) {
    __shared__ float4 sw[NLON];

    int t = blockIdx.y;
    int ptile = blockIdx.x % 3;
    int bcc = blockIdx.x / 3;
    int p = ptile * 256 + threadIdx.x;
    int bc0 = bcc * NBC;

    float acc[KK][NBC];
#pragma unroll
    for (int k = 0; k < KK; ++k)
#pragma unroll
        for (int b = 0; b < NBC; ++b) acc[k][b] = 0.f;

    // wave's lane-0 p (smallest p in wave -> largest r)
    int pw0 = __builtin_amdgcn_readfirstlane(p);

    for (int d = 0; d < LASPAN; ++d) {
        int row = t * LASPAN + d;
        int rmin = rmin_a[row];
        int rmax = rmax_a[row];
        int width = rmax - rmin + 1;
        if (width <= 0) continue;   // block-uniform
        int off = offs[row];
        if (off + width > CAP) width = CAP - off;  // overflow guard
        if (width <= 0) continue;

        __syncthreads();
        for (int j = threadIdx.x; j < width; j += 256)
            sw[j] = *reinterpret_cast<const float4*>(stream + (size_t)(off + j) * 4);
        __syncthreads();

        int la = t + d - 4;
        const float* xb[NBC];
#pragma unroll
        for (int b = 0; b < NBC; ++b)
            xb[b] = x + ((size_t)(bc0 + b) * NLAT + la) * NLON;

        // r = (rmin - 1 - p) mod 720, then r increments by 1 per window step
        int c = rmin - 1 - p;                // in [-768, 718]
        int r = c + ((c < 0) ? 720 : 0);
        r += (r < 0) ? 720 : 0;

        // scalar: wave-max r at j=0, normalized to [0,720)
        int rtw = rmin - 1 - pw0;
        rtw += (rtw < 0) ? 720 : 0;
        rtw += (rtw < 0) ? 720 : 0;

        int j = 0;
        while (j + 4 <= width) {
            int m = rtw + j;                 // < 1440
            m -= (m >= 720) ? 720 : 0;
            if (m >= 63 && m <= 716) {
                // all lanes in wave have r <= 716: safe 4-wide loads
                float4 w0 = sw[j], w1 = sw[j + 1], w2 = sw[j + 2], w3 = sw[j + 3];
#pragma unroll
                for (int b = 0; b < NBC; ++b) {
                    f4u xq = *reinterpret_cast<const f4u*>(xb[b] + r);
                    acc[0][b] = fmaf(w3.x, xq.w, fmaf(w2.x, xq.z,
                                 fmaf(w1.x, xq.y, fmaf(w0.x, xq.x, acc[0][b]))));
                    acc[1][b] = fmaf(w3.y, xq.w, fmaf(w2.y, xq.z,
                                 fmaf(w1.y, xq.y, fmaf(w0.y, xq.x, acc[1][b]))));
                    acc[2][b] = fmaf(w3.z, xq.w, fmaf(w2.z, xq.z,
                                 fmaf(w1.z, xq.y, fmaf(w0.z, xq.x, acc[2][b]))));
                }
                r += 4;
                r -= (r >= 720) ? 720 : 0;
                j += 4;
            } else {
#pragma unroll
                for (int u = 0; u < 4; ++u) {
                    float4 w = sw[j];
#pragma unroll
                    for (int b = 0; b < NBC; ++b) {
                        float xv = xb[b][r];
                        acc[0][b] = fmaf(w.x, xv, acc[0][b]);
                        acc[1][b] = fmaf(w.y, xv, acc[1][b]);
                        acc[2][b] = fmaf(w.z, xv, acc[2][b]);
                    }
                    r += 1;
                    r = (r == 720) ? 0 : r;
                    j += 1;
                }
            }
        }
        while (j < width) {
            float4 w = sw[j];
#pragma unroll
            for (int b = 0; b < NBC; ++b) {
                float xv = xb[b][r];
                acc[0][b] = fmaf(w.x, xv, acc[0][b]);
                acc[1][b] = fmaf(w.y, xv, acc[1][b]);
                acc[2][b] = fmaf(w.z, xv, acc[2][b]);
            }
            r += 1;
            r = (r == 720) ? 0 : r;
            j += 1;
        }
    }

    if (p < NLON) {
        size_t tp = (size_t)t * NLON + p;
#pragma unroll
        for (int b = 0; b < NBC; ++b) {
#pragma unroll
            for (int k = 0; k < KK; ++k) {
                out[((size_t)(bc0 + b) * KK + k) * (size_t)(NLAT * NLON) + tp] = acc[k][b];
            }
        }
    }
}

// ---------------- launcher ----------------

extern "C" void kernel_launch(void* const* d_in, const int* in_sizes, int n_in,
                              void* d_out, int out_size, void* d_ws, size_t ws_size,
                              hipStream_t stream) {
    const float* x = (const float*)d_in[0];
    const float* pv = (const float*)d_in[1];
    const int* pk = (const int*)d_in[2];
    const int* pt = (const int*)d_in[3];
    const int* pla = (const int*)d_in[4];
    const int* plo = (const int*)d_in[5];
    float* out = (float*)d_out;

    int nnz = in_sizes[1];

    int* wsI = (int*)d_ws;
    int* rmin = wsI + 0;        // [3249]
    int* rmax = wsI + 4096;     // [3249]
    int* offs = wsI + 8192;     // [3250]
    float* wstream = (float*)(wsI + 16384);  // [CAP * 4] floats (float4/slot)

    int nb = (nnz + 255) / 256;

    init_rows_kernel<<<(NROWS + 255) / 256, 256, 0, stream>>>(rmin, rmax);
    minmax_kernel<<<nb, 256, 0, stream>>>(pt, pla, plo, nnz, rmin, rmax);
    scan_rows_kernel<<<1, 256, 0, stream>>>(rmin, rmax, offs);
    zero_stream_kernel<<<1024, 256, 0, stream>>>(offs, (float4*)wstream);
    scatter_w_kernel<<<nb, 256, 0, stream>>>(pk, pt, pla, plo, pv, nnz, rmin, offs, wstream);

    dim3 grid(48, NLAT, 1);
    dconv_fir_kernel<<<grid, 256, 0, stream>>>(x, rmin, rmax, offs, wstream, out);
}

// Round 3
// 539.064 us; speedup vs baseline: 3.5398x; 2.2544x over previous
//
#include <hip/hip_runtime.h>

// DiscreteContinuousConvS2 via bf16 MFMA:
// out[bc, k, t, p] = sum_{taps (k,t,la,lo)} v * x[bc, la, (lo - 1 - p) mod 720]
// B*C = 128, K = 3, nlat = 361, nlon = 720.
//
// Per (t, d=la-t+4) the tap set over lo is a contiguous interval [rmin, rmax].
// For a 48-wide p-tile: linear m-index m_tilde = m_start + e (m_start 8-aligned,
// = rmin-48-p0-shift), weight index j_tilde = e + (p-p0) - 47 - shift into a
// zero-padded per-(t,d) window handles the mod-720 wrap exactly (W <= 720).
// A = Toeplitz weight fragments (built per-lane from f32 LDS window),
// B = x rows reg-staged f32->bf16 into XOR-swizzled LDS, D accumulated fp32.

#define NLAT 361
#define NLON 720
#define KK 3
#define LASPAN 9
#define NROWS (NLAT * LASPAN)     // 3249
#define CAP 524288                // max total window slots
#define PTILE 48
#define NT 384                    // 6 waves: 3 p-subtiles x 2 bc-halves
#define SWN 864                   // per-k padded weight window (f32 slots)

typedef __attribute__((ext_vector_type(8))) short bf16x8;
typedef __attribute__((ext_vector_type(4))) float f32x4;
typedef __attribute__((ext_vector_type(4))) unsigned int u32x4;

// ---------------- build kernels (same infra as round 2) ----------------

__global__ void init_rows_kernel(int* __restrict__ rmin, int* __restrict__ rmax) {
    int i = blockIdx.x * 256 + threadIdx.x;
    if (i < NROWS) { rmin[i] = NLON; rmax[i] = -1; }
}

__global__ void minmax_kernel(const int* __restrict__ pt, const int* __restrict__ pla,
                              const int* __restrict__ plo, int nnz,
                              int* __restrict__ rmin, int* __restrict__ rmax) {
    int i = blockIdx.x * 256 + threadIdx.x;
    if (i >= nnz) return;
    int t = pt[i], la = pla[i], lo = plo[i];
    int d = la - t + 4;
    if (d < 0 || d >= LASPAN) return;
    int row = t * LASPAN + d;
    atomicMin(&rmin[row], lo);
    atomicMax(&rmax[row], lo);
}

__global__ void scan_rows_kernel(const int* __restrict__ rmin, const int* __restrict__ rmax,
                                 int* __restrict__ offs) {
    __shared__ int part[256];
    int tid = threadIdx.x;
    int c[13];
    int s = 0;
    int i0 = tid * 13;
#pragma unroll
    for (int u = 0; u < 13; ++u) {
        int idx = i0 + u;
        int w = 0;
        if (idx < NROWS) {
            w = rmax[idx] - rmin[idx] + 1;
            if (w < 0) w = 0;
        }
        c[u] = w;
        s += w;
    }
    part[tid] = s;
    __syncthreads();
    for (int d = 1; d < 256; d <<= 1) {
        int v = part[tid];
        int w = (tid >= d) ? part[tid - d] : 0;
        __syncthreads();
        part[tid] = v + w;
        __syncthreads();
    }
    int excl = part[tid] - s;
#pragma unroll
    for (int u = 0; u < 13; ++u) {
        int idx = i0 + u;
        if (idx < NROWS) offs[idx] = excl;
        excl += c[u];
    }
    if (tid == 255) offs[NROWS] = excl;
}

__global__ void zero_stream_kernel(const int* __restrict__ offs, float4* __restrict__ stream4) {
    int total = offs[NROWS];
    if (total > CAP) total = CAP;
    for (int i = blockIdx.x * 256 + threadIdx.x; i < total; i += gridDim.x * 256)
        stream4[i] = make_float4(0.f, 0.f, 0.f, 0.f);
}

__global__ void scatter_w_kernel(const int* __restrict__ pk, const int* __restrict__ pt,
                                 const int* __restrict__ pla, const int* __restrict__ plo,
                                 const float* __restrict__ pv, int nnz,
                                 const int* __restrict__ rmin, const int* __restrict__ offs,
                                 float* __restrict__ stream) {
    int i = blockIdx.x * 256 + threadIdx.x;
    if (i >= nnz) return;
    int t = pt[i], la = pla[i], lo = plo[i], k = pk[i];
    int d = la - t + 4;
    if (d < 0 || d >= LASPAN) return;
    int row = t * LASPAN + d;
    int slot = offs[row] + (lo - rmin[row]);
    if (slot >= 0 && slot < CAP && k >= 0 && k < 4)
        stream[(size_t)slot * 4 + k] = pv[i];
}

// ---------------- main MFMA kernel ----------------
// grid: (15 p-tiles, 361 t-remapped); block: 384 threads (6 waves).
// wave w: psub = w>>1 in {0,1,2} (16-p row block), bch = w&1 (64-bc half).

__device__ inline unsigned int bf16pair_rne(float lo, float hi) {
    unsigned int a = __builtin_bit_cast(unsigned int, lo);
    unsigned int b = __builtin_bit_cast(unsigned int, hi);
    a = a + 0x7fffu + ((a >> 16) & 1u);
    b = b + 0x7fffu + ((b >> 16) & 1u);
    return (a >> 16) | (b & 0xffff0000u);
}

__global__ __launch_bounds__(NT) void dconv_mfma_kernel(
    const float* __restrict__ x, const int* __restrict__ rmin_a,
    const int* __restrict__ rmax_a, const int* __restrict__ offs,
    const float* __restrict__ stream, float* __restrict__ out) {
    // B tile: 128 bc rows x 64 m (bf16), XOR-swizzled within each 128B row.
    __shared__ __attribute__((aligned(16))) unsigned char sB[128 * 128];
    // Weight windows, f32 (values pre-rounded to bf16), zero-padded.
    __shared__ __attribute__((aligned(16))) float sW[KK * SWN];

    int bx = blockIdx.x;
    int y = blockIdx.y;
    int t = (y & 1) ? (360 - (y >> 1)) : (y >> 1);   // heavy polar t's first
    int p0 = bx * PTILE;
    int tid = threadIdx.x;
    int lane = tid & 63;
    int w = tid >> 6;
    int psub = w >> 1;
    int bc0w = (w & 1) * 64;

    f32x4 acc[4][KK];
#pragma unroll
    for (int n = 0; n < 4; ++n)
#pragma unroll
        for (int k = 0; k < KK; ++k) acc[n][k] = (f32x4){0.f, 0.f, 0.f, 0.f};

    int l15 = lane & 15;
    int l4 = lane >> 4;

    for (int d = 0; d < LASPAN; ++d) {
        int row = t * LASPAN + d;
        int rmin = rmin_a[row];
        int rmax = rmax_a[row];
        int W = rmax - rmin + 1;
        if (W <= 0) continue;            // block-uniform
        int la = t + d - 4;
        int off = offs[row];
        if (off + W > CAP) continue;     // overflow guard (never expected)

        int ms0 = rmin - 48 - p0;                 // >= -720
        int shift = ((ms0 % 8) + 8) % 8;
        int L = W + 47 + shift;
        int nK = (L + 31) >> 5;
        int nC = (nK + 1) >> 1;
        int mbase = (((ms0 - shift) % 720) + 720) % 720;   // 8-aligned

        // ---- build zero-padded weight windows (f32, pre-rounded to bf16) ----
        __syncthreads();   // previous d's A-frag reads of sW done
        int wcnt = W + 136;
        for (int s = tid; s < wcnt; s += NT) {
            int j = s - 56;
            float wx = 0.f, wy = 0.f, wz = 0.f;
            if (j >= 0 && j < W) {
                const float* q = stream + (size_t)(off + j) * 4;
                wx = q[0]; wy = q[1]; wz = q[2];
            }
            unsigned int ux = (__builtin_bit_cast(unsigned int, wx) + 0x7fffu +
                               ((__builtin_bit_cast(unsigned int, wx) >> 16) & 1u)) & 0xffff0000u;
            unsigned int uy = (__builtin_bit_cast(unsigned int, wy) + 0x7fffu +
                               ((__builtin_bit_cast(unsigned int, wy) >> 16) & 1u)) & 0xffff0000u;
            unsigned int uz = (__builtin_bit_cast(unsigned int, wz) + 0x7fffu +
                               ((__builtin_bit_cast(unsigned int, wz) >> 16) & 1u)) & 0xffff0000u;
            sW[0 * SWN + s] = __builtin_bit_cast(float, ux);
            sW[1 * SWN + s] = __builtin_bit_cast(float, uy);
            sW[2 * SWN + s] = __builtin_bit_cast(float, uz);
        }
        __syncthreads();

        const float* xla = x + (size_t)la * NLON;   // + bc*361*720 later

        for (int c = 0; c < nC; ++c) {
            __syncthreads();   // previous chunk's B reads done
            // ---- stage B chunk: 128 bc x 64 m, f32 -> bf16, swizzled ds_write ----
#pragma unroll
            for (int pass = 0; pass < 3; ++pass) {
                int slot = pass * NT + tid;
                if (slot < 1024) {
                    int bc = slot >> 3;
                    int mo = (slot & 7) * 8;
                    int mg = mbase + c * 64 + mo;
                    mg -= (mg >= 720) ? 720 : 0;
                    mg -= (mg >= 720) ? 720 : 0;
                    mg -= (mg >= 720) ? 720 : 0;
                    const float* src = xla + (size_t)bc * (NLAT * NLON) + mg;
                    f32x4 a = *(const f32x4*)(src);
                    f32x4 b = *(const f32x4*)(src + 4);
                    u32x4 q;
                    q.x = bf16pair_rne(a.x, a.y);
                    q.y = bf16pair_rne(a.z, a.w);
                    q.z = bf16pair_rne(b.x, b.y);
                    q.w = bf16pair_rne(b.z, b.w);
                    int cw = (mo * 2) ^ ((bc & 7) << 4);
                    *(u32x4*)(sB + bc * 128 + cw) = q;
                }
            }
            __syncthreads();

            int ksmax = nK - c * 2;
            if (ksmax > 2) ksmax = 2;
            for (int ks = 0; ks < ksmax; ++ks) {
                int e0 = c * 64 + ks * 32;
                // ---- A fragments: per-lane 8 consecutive padded-window slots ----
                int sbase = e0 + l4 * 8 + psub * 16 + l15 + 9 - shift;
                bf16x8 af[KK];
#pragma unroll
                for (int k = 0; k < KK; ++k) {
                    const float* wp = sW + k * SWN + sbase;
                    unsigned int u0 = __builtin_bit_cast(unsigned int, wp[0]);
                    unsigned int u1 = __builtin_bit_cast(unsigned int, wp[1]);
                    unsigned int u2 = __builtin_bit_cast(unsigned int, wp[2]);
                    unsigned int u3 = __builtin_bit_cast(unsigned int, wp[3]);
                    unsigned int u4 = __builtin_bit_cast(unsigned int, wp[4]);
                    unsigned int u5 = __builtin_bit_cast(unsigned int, wp[5]);
                    unsigned int u6 = __builtin_bit_cast(unsigned int, wp[6]);
                    unsigned int u7 = __builtin_bit_cast(unsigned int, wp[7]);
                    u32x4 q;
                    q.x = (u0 >> 16) | u1;
                    q.y = (u2 >> 16) | u3;
                    q.z = (u4 >> 16) | u5;
                    q.w = (u6 >> 16) | u7;
                    af[k] = __builtin_bit_cast(bf16x8, q);
                }
                // ---- B fragments + MFMA ----
                int colbase = (ks * 32) * 2 + l4 * 16;
#pragma unroll
                for (int n = 0; n < 4; ++n) {
                    int brow = bc0w + n * 16 + l15;
                    int colb = colbase ^ ((brow & 7) << 4);
                    bf16x8 bfv = *(const bf16x8*)(sB + brow * 128 + colb);
                    acc[n][0] = __builtin_amdgcn_mfma_f32_16x16x32_bf16(af[0], bfv, acc[n][0], 0, 0, 0);
                    acc[n][1] = __builtin_amdgcn_mfma_f32_16x16x32_bf16(af[1], bfv, acc[n][1], 0, 0, 0);
                    acc[n][2] = __builtin_amdgcn_mfma_f32_16x16x32_bf16(af[2], bfv, acc[n][2], 0, 0, 0);
                }
            }
        }
    }

    // ---- epilogue: D col = lane&15 (bc), row = (lane>>4)*4 + reg (p) ----
    int p = p0 + psub * 16 + l4 * 4;
#pragma unroll
    for (int n = 0; n < 4; ++n) {
        int bc = bc0w + n * 16 + l15;
#pragma unroll
        for (int k = 0; k < KK; ++k) {
            float* o = out + (((size_t)bc * KK + k) * NLAT + t) * NLON + p;
            *(f32x4*)o = acc[n][k];
        }
    }
}

// ---------------- launcher ----------------

extern "C" void kernel_launch(void* const* d_in, const int* in_sizes, int n_in,
                              void* d_out, int out_size, void* d_ws, size_t ws_size,
                              hipStream_t stream) {
    const float* x = (const float*)d_in[0];
    const float* pv = (const float*)d_in[1];
    const int* pk = (const int*)d_in[2];
    const int* pt = (const int*)d_in[3];
    const int* pla = (const int*)d_in[4];
    const int* plo = (const int*)d_in[5];
    float* out = (float*)d_out;

    int nnz = in_sizes[1];

    int* wsI = (int*)d_ws;
    int* rmin = wsI + 0;        // [3249]
    int* rmax = wsI + 4096;     // [3249]
    int* offs = wsI + 8192;     // [3250]
    float* wstream = (float*)(wsI + 16384);  // [CAP * 4] floats (float4/slot)

    int nb = (nnz + 255) / 256;

    init_rows_kernel<<<(NROWS + 255) / 256, 256, 0, stream>>>(rmin, rmax);
    minmax_kernel<<<nb, 256, 0, stream>>>(pt, pla, plo, nnz, rmin, rmax);
    scan_rows_kernel<<<1, 256, 0, stream>>>(rmin, rmax, offs);
    zero_stream_kernel<<<1024, 256, 0, stream>>>(offs, (float4*)wstream);
    scatter_w_kernel<<<nb, 256, 0, stream>>>(pk, pt, pla, plo, pv, nnz, rmin, offs, wstream);

    dim3 grid(NLON / PTILE, NLAT, 1);
    dconv_mfma_kernel<<<grid, NT, 0, stream>>>(x, rmin, rmax, offs, wstream, out);
}

// Round 4
// 517.084 us; speedup vs baseline: 3.6902x; 1.0425x over previous
//
#include <hip/hip_runtime.h>

// DiscreteContinuousConvS2 via bf16 MFMA (R4):
// out[bc, k, t, p] = sum_{taps (k,t,la,lo)} v * x[bc, la, (lo - 1 - p) mod 720]
// B*C = 128, K = 3, nlat = 361, nlon = 720.
//
// R4 changes vs R3:
//  - A-fragments read as 4 ds_read_b32 from dual-parity bf16-packed windows
//    (was 8 ds_read_b32 + pack VALU per k; 24 -> 12 b32/K-step/wave total).
//  - Per-wave K-step clipping (skip K-steps whose A sub-band is all zero).
//  - x pre-converted to bf16 in workspace (staging: 16B loads, no cvt VALU,
//    66MB L3-resident footprint). f32 fallback if ws too small.
//  - 2 barriers per (t,d) instead of 4; init+zero merged.

#define NLAT 361
#define NLON 720
#define KK 3
#define LASPAN 9
#define NROWS (NLAT * LASPAN)     // 3249
#define CAP 524288                // max total window slots
#define PTILE 48
#define NT 384                    // 6 waves: 3 p-subtiles x 2 bc-halves
#define SWN2 448                  // u32 slots per parity copy per k

typedef __attribute__((ext_vector_type(8))) short bf16x8;
typedef __attribute__((ext_vector_type(4))) float f32x4;
typedef __attribute__((ext_vector_type(4))) unsigned int u32x4;

// ---------------- build kernels ----------------

__global__ void init_zero_kernel(int* __restrict__ rmin, int* __restrict__ rmax,
                                 float4* __restrict__ stream4) {
    int i = blockIdx.x * 256 + threadIdx.x;
    if (i < NROWS) { rmin[i] = NLON; rmax[i] = -1; }
    if (i < CAP) stream4[i] = make_float4(0.f, 0.f, 0.f, 0.f);
}

__global__ void minmax_kernel(const int* __restrict__ pt, const int* __restrict__ pla,
                              const int* __restrict__ plo, int nnz,
                              int* __restrict__ rmin, int* __restrict__ rmax) {
    int i = blockIdx.x * 256 + threadIdx.x;
    if (i >= nnz) return;
    int t = pt[i], la = pla[i], lo = plo[i];
    int d = la - t + 4;
    if (d < 0 || d >= LASPAN) return;
    int row = t * LASPAN + d;
    atomicMin(&rmin[row], lo);
    atomicMax(&rmax[row], lo);
}

__global__ void scan_rows_kernel(const int* __restrict__ rmin, const int* __restrict__ rmax,
                                 int* __restrict__ offs) {
    __shared__ int part[256];
    int tid = threadIdx.x;
    int c[13];
    int s = 0;
    int i0 = tid * 13;
#pragma unroll
    for (int u = 0; u < 13; ++u) {
        int idx = i0 + u;
        int w = 0;
        if (idx < NROWS) {
            w = rmax[idx] - rmin[idx] + 1;
            if (w < 0) w = 0;
        }
        c[u] = w;
        s += w;
    }
    part[tid] = s;
    __syncthreads();
    for (int d = 1; d < 256; d <<= 1) {
        int v = part[tid];
        int w = (tid >= d) ? part[tid - d] : 0;
        __syncthreads();
        part[tid] = v + w;
        __syncthreads();
    }
    int excl = part[tid] - s;
#pragma unroll
    for (int u = 0; u < 13; ++u) {
        int idx = i0 + u;
        if (idx < NROWS) offs[idx] = excl;
        excl += c[u];
    }
    if (tid == 255) offs[NROWS] = excl;
}

__global__ void scatter_w_kernel(const int* __restrict__ pk, const int* __restrict__ pt,
                                 const int* __restrict__ pla, const int* __restrict__ plo,
                                 const float* __restrict__ pv, int nnz,
                                 const int* __restrict__ rmin, const int* __restrict__ offs,
                                 float* __restrict__ stream) {
    int i = blockIdx.x * 256 + threadIdx.x;
    if (i >= nnz) return;
    int t = pt[i], la = pla[i], lo = plo[i], k = pk[i];
    int d = la - t + 4;
    if (d < 0 || d >= LASPAN) return;
    int row = t * LASPAN + d;
    int slot = offs[row] + (lo - rmin[row]);
    if (slot >= 0 && slot < CAP && k >= 0 && k < 4)
        stream[(size_t)slot * 4 + k] = pv[i];
}

__device__ inline unsigned int bf16pair_rne(float lo, float hi) {
    unsigned int a = __builtin_bit_cast(unsigned int, lo);
    unsigned int b = __builtin_bit_cast(unsigned int, hi);
    a = a + 0x7fffu + ((a >> 16) & 1u);
    b = b + 0x7fffu + ((b >> 16) & 1u);
    return (a >> 16) | (b & 0xffff0000u);
}

// x (f32) -> xb (bf16, rne), 8 elems/thread/iter
__global__ void cvt_x_kernel(const float* __restrict__ x, unsigned int* __restrict__ xb,
                             int n8) {
    for (int i = blockIdx.x * 256 + threadIdx.x; i < n8; i += gridDim.x * 256) {
        f32x4 a = *(const f32x4*)(x + (size_t)i * 8);
        f32x4 b = *(const f32x4*)(x + (size_t)i * 8 + 4);
        u32x4 q;
        q.x = bf16pair_rne(a.x, a.y);
        q.y = bf16pair_rne(a.z, a.w);
        q.z = bf16pair_rne(b.x, b.y);
        q.w = bf16pair_rne(b.z, b.w);
        *(u32x4*)(xb + (size_t)i * 4) = q;
    }
}

// ---------------- main MFMA kernel ----------------
// grid: (15 p-tiles, 361 t-remapped); block: 384 threads (6 waves).
// wave w: psub = w>>1 in {0,1,2} (16-p row block), bch = w&1 (64-bc half).

template <int USEBF16>
__global__ __launch_bounds__(NT) void dconv_mfma_kernel(
    const float* __restrict__ x, const unsigned short* __restrict__ xb,
    const int* __restrict__ rmin_a, const int* __restrict__ rmax_a,
    const int* __restrict__ offs, const float* __restrict__ stream,
    float* __restrict__ out) {
    // B tile: 128 bc rows x 64 m (bf16), XOR-swizzled within each 128B row.
    __shared__ __attribute__((aligned(16))) unsigned char sB[128 * 128];
    // Dual-parity bf16-packed weight windows: [k][P][q], cp[P][q]=pack(w[2q+P],w[2q+1+P])
    __shared__ unsigned int sWp[KK * 2 * SWN2];

    int bx = blockIdx.x;
    int y = blockIdx.y;
    int t = (y & 1) ? (360 - (y >> 1)) : (y >> 1);   // heavy polar t's first
    int p0 = bx * PTILE;
    int tid = threadIdx.x;
    int lane = tid & 63;
    int w = tid >> 6;
    int psub = w >> 1;
    int bc0w = (w & 1) * 64;

    f32x4 acc[4][KK];
#pragma unroll
    for (int n = 0; n < 4; ++n)
#pragma unroll
        for (int k = 0; k < KK; ++k) acc[n][k] = (f32x4){0.f, 0.f, 0.f, 0.f};

    int l15 = lane & 15;
    int l4 = lane >> 4;

    for (int d = 0; d < LASPAN; ++d) {
        int row = t * LASPAN + d;
        int rmin = rmin_a[row];
        int rmax = rmax_a[row];
        int W = rmax - rmin + 1;
        if (W <= 0) continue;            // block-uniform
        int la = t + d - 4;
        int off = offs[row];
        if (off + W > CAP) continue;     // overflow guard (never expected)

        int ms0 = rmin - 48 - p0;                 // >= -720
        int shift = ((ms0 % 8) + 8) % 8;
        int L = W + 47 + shift;
        int nK = (L + 31) >> 5;
        int nC = (nK + 1) >> 1;
        int mbase = (((ms0 - shift) % 720) + 720) % 720;   // 8-aligned

        // per-wave A sub-band -> K-step clip range
        int s_off = psub * 16 + 9 - shift;
        int ks_lo = (9 - s_off + 31) >> 5;
        if (ks_lo < 0) ks_lo = 0;
        int ks_hi = (55 + W - s_off) >> 5;
        if (ks_hi > nK - 1) ks_hi = nK - 1;

        __syncthreads();   // prior d/chunk reads of sWp & sB done

        // ---- build dual-parity packed weight windows ----
        {
            const float4* s4 = (const float4*)stream;
            int npar = (W + 156) >> 1;           // q-range per parity copy
            int tot = npar * 2;
            for (int idx = tid; idx < tot; idx += NT) {
                int P = idx & 1;
                int q = idx >> 1;
                int j0 = 2 * q + P - 56;
                int j1 = j0 + 1;
                float4 f0 = (j0 >= 0 && j0 < W) ? s4[off + j0] : make_float4(0, 0, 0, 0);
                float4 f1 = (j1 >= 0 && j1 < W) ? s4[off + j1] : make_float4(0, 0, 0, 0);
                sWp[0 * 2 * SWN2 + P * SWN2 + q] = bf16pair_rne(f0.x, f1.x);
                sWp[1 * 2 * SWN2 + P * SWN2 + q] = bf16pair_rne(f0.y, f1.y);
                sWp[2 * 2 * SWN2 + P * SWN2 + q] = bf16pair_rne(f0.z, f1.z);
            }
        }

        // ---- stage chunk 0 (fused in same barrier interval) ----
        {
            int c = 0;
#pragma unroll
            for (int pass = 0; pass < 3; ++pass) {
                int slot = pass * NT + tid;
                if (slot < 1024) {
                    int bc = slot >> 3;
                    int mo = (slot & 7) * 8;
                    int mg = mbase + c * 64 + mo;
                    mg -= (mg >= 720) ? 720 : 0;
                    mg -= (mg >= 720) ? 720 : 0;
                    mg -= (mg >= 720) ? 720 : 0;
                    u32x4 q;
                    if (USEBF16) {
                        const unsigned short* src =
                            xb + ((size_t)bc * NLAT + la) * NLON + mg;
                        q = *(const u32x4*)src;
                    } else {
                        const float* src = x + ((size_t)bc * NLAT + la) * NLON + mg;
                        f32x4 a = *(const f32x4*)(src);
                        f32x4 b = *(const f32x4*)(src + 4);
                        q.x = bf16pair_rne(a.x, a.y);
                        q.y = bf16pair_rne(a.z, a.w);
                        q.z = bf16pair_rne(b.x, b.y);
                        q.w = bf16pair_rne(b.z, b.w);
                    }
                    int cw = (mo * 2) ^ ((bc & 7) << 4);
                    *(u32x4*)(sB + bc * 128 + cw) = q;
                }
            }
        }
        __syncthreads();

        for (int c = 0; c < nC; ++c) {
            if (c > 0) {
                __syncthreads();   // previous chunk's B reads done
#pragma unroll
                for (int pass = 0; pass < 3; ++pass) {
                    int slot = pass * NT + tid;
                    if (slot < 1024) {
                        int bc = slot >> 3;
                        int mo = (slot & 7) * 8;
                        int mg = mbase + c * 64 + mo;
                        mg -= (mg >= 720) ? 720 : 0;
                        mg -= (mg >= 720) ? 720 : 0;
                        mg -= (mg >= 720) ? 720 : 0;
                        u32x4 q;
                        if (USEBF16) {
                            const unsigned short* src =
                                xb + ((size_t)bc * NLAT + la) * NLON + mg;
                            q = *(const u32x4*)src;
                        } else {
                            const float* src = x + ((size_t)bc * NLAT + la) * NLON + mg;
                            f32x4 a = *(const f32x4*)(src);
                            f32x4 b = *(const f32x4*)(src + 4);
                            q.x = bf16pair_rne(a.x, a.y);
                            q.y = bf16pair_rne(a.z, a.w);
                            q.z = bf16pair_rne(b.x, b.y);
                            q.w = bf16pair_rne(b.z, b.w);
                        }
                        int cw = (mo * 2) ^ ((bc & 7) << 4);
                        *(u32x4*)(sB + bc * 128 + cw) = q;
                    }
                }
                __syncthreads();
            }

            int ksmax = nK - c * 2;
            if (ksmax > 2) ksmax = 2;
            for (int ksl = 0; ksl < ksmax; ++ksl) {
                int ks = c * 2 + ksl;
                if (ks < ks_lo || ks > ks_hi) continue;   // wave-uniform skip
                int e0 = ks * 32;
                // ---- A fragments: 4 consecutive u32 from parity copy ----
                int s = e0 + l4 * 8 + s_off + l15;
                int P = s & 1;
                int qq = s >> 1;
                bf16x8 af[KK];
#pragma unroll
                for (int k = 0; k < KK; ++k) {
                    const unsigned int* wp = sWp + k * (2 * SWN2) + P * SWN2 + qq;
                    u32x4 q;
                    q.x = wp[0];
                    q.y = wp[1];
                    q.z = wp[2];
                    q.w = wp[3];
                    af[k] = __builtin_bit_cast(bf16x8, q);
                }
                // ---- B fragments + MFMA ----
                int colbase = ksl * 64 + l4 * 16;
#pragma unroll
                for (int n = 0; n < 4; ++n) {
                    int brow = bc0w + n * 16 + l15;
                    int colb = colbase ^ ((brow & 7) << 4);
                    bf16x8 bfv = *(const bf16x8*)(sB + brow * 128 + colb);
                    acc[n][0] = __builtin_amdgcn_mfma_f32_16x16x32_bf16(af[0], bfv, acc[n][0], 0, 0, 0);
                    acc[n][1] = __builtin_amdgcn_mfma_f32_16x16x32_bf16(af[1], bfv, acc[n][1], 0, 0, 0);
                    acc[n][2] = __builtin_amdgcn_mfma_f32_16x16x32_bf16(af[2], bfv, acc[n][2], 0, 0, 0);
                }
            }
        }
    }

    // ---- epilogue: D col = lane&15 (bc), row = (lane>>4)*4 + reg (p) ----
    int p = p0 + psub * 16 + l4 * 4;
#pragma unroll
    for (int n = 0; n < 4; ++n) {
        int bc = bc0w + n * 16 + l15;
#pragma unroll
        for (int k = 0; k < KK; ++k) {
            float* o = out + (((size_t)bc * KK + k) * NLAT + t) * NLON + p;
            *(f32x4*)o = acc[n][k];
        }
    }
}

// ---------------- launcher ----------------

extern "C" void kernel_launch(void* const* d_in, const int* in_sizes, int n_in,
                              void* d_out, int out_size, void* d_ws, size_t ws_size,
                              hipStream_t stream) {
    const float* x = (const float*)d_in[0];
    const float* pv = (const float*)d_in[1];
    const int* pk = (const int*)d_in[2];
    const int* pt = (const int*)d_in[3];
    const int* pla = (const int*)d_in[4];
    const int* plo = (const int*)d_in[5];
    float* out = (float*)d_out;

    int nnz = in_sizes[1];

    int* wsI = (int*)d_ws;
    int* rmin = wsI + 0;        // [3249]
    int* rmax = wsI + 4096;     // [3249]
    int* offs = wsI + 8192;     // [3250]
    float* wstream = (float*)(wsI + 16384);  // [CAP*4] floats (float4/slot)
    size_t xb_off = 65536 + (size_t)CAP * 16;              // bytes
    size_t xb_bytes = (size_t)128 * NLAT * NLON * 2;       // 66.5 MB
    int use_bf16 = (ws_size >= xb_off + xb_bytes) ? 1 : 0;
    unsigned short* xb = (unsigned short*)((char*)d_ws + xb_off);

    int nb = (nnz + 255) / 256;

    init_zero_kernel<<<(CAP + 255) / 256, 256, 0, stream>>>(rmin, rmax, (float4*)wstream);
    minmax_kernel<<<nb, 256, 0, stream>>>(pt, pla, plo, nnz, rmin, rmax);
    scan_rows_kernel<<<1, 256, 0, stream>>>(rmin, rmax, offs);
    scatter_w_kernel<<<nb, 256, 0, stream>>>(pk, pt, pla, plo, pv, nnz, rmin, offs, wstream);

    dim3 grid(NLON / PTILE, NLAT, 1);
    if (use_bf16) {
        int n8 = 128 * NLAT * NLON / 8;
        cvt_x_kernel<<<2048, 256, 0, stream>>>(x, (unsigned int*)xb, n8);
        dconv_mfma_kernel<1><<<grid, NT, 0, stream>>>(x, xb, rmin, rmax, offs, wstream, out);
    } else {
        dconv_mfma_kernel<0><<<grid, NT, 0, stream>>>(x, xb, rmin, rmax, offs, wstream, out);
    }
}